// Round 6
// baseline (113.353 us; speedup 1.0000x reference)
//
#include <hip/hip_runtime.h>
#include <hip/hip_cooperative_groups.h>

namespace cg = cooperative_groups;

#define NB 384          // batch
#define ND 512          // dim
#define KS 8            // k-slices
#define FLT_BIG 3.0e38f

// ws layout (floats): Gp[8][384][384] @ 0 ; sq[384] ; npos[1]   (< 5 MB)

__global__ __launch_bounds__(256) void fused_kernel(const float* __restrict__ V,
                                                    const int* __restrict__ labels,
                                                    float* __restrict__ Gp,
                                                    float* __restrict__ sq,
                                                    float* __restrict__ npos,
                                                    float* __restrict__ out) {
  __shared__ float As[64][68];
  __shared__ float Bs[64][68];
  const int bx = blockIdx.x;
  const int tid = threadIdx.x;

  // ---------------- phase 1 ----------------
  if (bx < 168) {
    // split-K gram partials: 8 k-slices x 21 upper tile-pairs, mirror-stored
    const int ks = bx / 21;
    int rem = bx % 21;
    int ti = 0, cnt = 6;
    while (rem >= cnt) { rem -= cnt; --cnt; ++ti; }   // triangular tile pair
    const int tj = ti + rem;
    const int a0 = ti * 64, b0 = tj * 64, k0 = ks * 64;

#pragma unroll
    for (int it = 0; it < 4; ++it) {
      int f = tid + it * 256;            // float4 id 0..1023
      int row = f >> 4, c4 = (f & 15) << 2;
      *(float4*)&As[row][c4] = *(const float4*)&V[(size_t)(a0 + row) * ND + k0 + c4];
      *(float4*)&Bs[row][c4] = *(const float4*)&V[(size_t)(b0 + row) * ND + k0 + c4];
    }
    __syncthreads();

    const int tx = tid & 15, ty = tid >> 4;
    float acc[4][4] = {};
#pragma unroll
    for (int kk = 0; kk < 64; kk += 4) {
      float4 av[4], bv[4];
#pragma unroll
      for (int i = 0; i < 4; ++i) {
        av[i] = *(const float4*)&As[ty + 16 * i][kk];
        bv[i] = *(const float4*)&Bs[tx + 16 * i][kk];
      }
#pragma unroll
      for (int i = 0; i < 4; ++i)
#pragma unroll
        for (int j = 0; j < 4; ++j) {
          acc[i][j] = fmaf(av[i].x, bv[j].x, acc[i][j]);
          acc[i][j] = fmaf(av[i].y, bv[j].y, acc[i][j]);
          acc[i][j] = fmaf(av[i].z, bv[j].z, acc[i][j]);
          acc[i][j] = fmaf(av[i].w, bv[j].w, acc[i][j]);
        }
    }
    float* Gk = Gp + (size_t)ks * NB * NB;
#pragma unroll
    for (int i = 0; i < 4; ++i)
#pragma unroll
      for (int j = 0; j < 4; ++j) {
        const int ar = a0 + ty + 16 * i, bc = b0 + tx + 16 * j;
        Gk[(size_t)ar * NB + bc] = acc[i][j];
        Gk[(size_t)bc * NB + ar] = acc[i][j];   // symmetric mirror (identical value)
      }
  } else if (bx < 174) {
    // sq for 64 rows: 4 lanes per row
    const int r = (bx - 168) * 64 + (tid >> 2);
    const int q = tid & 3;
    const float4* p = (const float4*)(V + (size_t)r * ND + q * 128);
    float s = 0.f;
#pragma unroll 8
    for (int i = 0; i < 32; ++i) {
      float4 v = p[i];
      s += v.x * v.x + v.y * v.y + v.z * v.z + v.w * v.w;
    }
    s += __shfl_xor(s, 1);
    s += __shfl_xor(s, 2);
    if (q == 0) sq[r] = s;
  } else if (bx == 174) {
    // num_pos = sum_c count[c]^2 - NB ; zero the output slot
    __shared__ int cnt[64];
    if (tid < 64) cnt[tid] = 0;
    __syncthreads();
    for (int i = tid; i < NB; i += 256) atomicAdd(&cnt[labels[i]], 1);
    __syncthreads();
    if (tid < 64) {
      int c = cnt[tid];
      int s = c * c;
#pragma unroll
      for (int off = 32; off; off >>= 1) s += __shfl_xor(s, off);
      if (tid == 0) {
        npos[0] = (float)(s - NB);
        out[0] = 0.0f;
      }
    }
  }

  // ---------------- grid-wide barrier ----------------
  cg::this_grid().sync();

  // ---------------- phase 2: one wave per row ----------------
  const int lane = tid & 63, wid = tid >> 6;
  const int a = bx * 4 + wid;
  if (a >= NB) return;

  const float sqa = sq[a];
  const int la = labels[a];

  float dk[6];
  int same[6];
  float neg_in = 0.0f;
#pragma unroll
  for (int i = 0; i < 6; ++i) {
    const int k = lane + (i << 6);
    float g = 0.f;
#pragma unroll
    for (int p = 0; p < KS; ++p) g += Gp[(size_t)p * NB * NB + (size_t)a * NB + k];
    float d2 = sqa + sq[k] - 2.0f * g;
    d2 = fmaxf(d2, 0.0f);
    float d = (d2 <= 0.0f) ? 0.0f : sqrtf(d2);
    if (k == a) d = 0.0f;               // zero diagonal (matches reference)
    dk[i] = d;
    same[i] = (labels[k] == la);
    if (!same[i]) neg_in = fmaxf(neg_in, d);   // row_min == 0 exactly
  }
#pragma unroll
  for (int off = 32; off; off >>= 1) neg_in = fmaxf(neg_in, __shfl_xor(neg_in, off));

  float rsum = 0.0f;
#pragma unroll 1
  for (int i = 0; i < 6; ++i) {
    const int k = lane + (i << 6);
    unsigned long long pm = __ballot(same[i] && (k != a));   // positives in this slice
    while (pm) {
      const int src = __builtin_ctzll(pm);
      pm &= pm - 1;
      const float db = __shfl(dk[i], src);   // d[a,b] broadcast
      float m = FLT_BIG;                     // min over negs with d[a,k] > db
#pragma unroll
      for (int t = 0; t < 6; ++t) {
        const float c = (!same[t] && dk[t] > db) ? dk[t] : FLT_BIG;
        m = fminf(m, c);
      }
#pragma unroll
      for (int off = 32; off; off >>= 1) m = fminf(m, __shfl_xor(m, off));
      const float semi = (m < 1.0e38f) ? m : neg_in;  // exists -> neg_out else neg_in
      rsum += fmaxf(db - semi + 1.0f, 0.0f);          // MARGIN = 1
    }
  }
  if (lane == 0) atomicAdd(out, rsum / npos[0]);
}

extern "C" void kernel_launch(void* const* d_in, const int* in_sizes, int n_in,
                              void* d_out, int out_size, void* d_ws, size_t ws_size,
                              hipStream_t stream) {
  const float* V = (const float*)d_in[0];
  const int* labels = (const int*)d_in[1];
  float* outp = (float*)d_out;
  float* Gp = (float*)d_ws;                         // 8*384*384 floats
  float* sq = Gp + (size_t)KS * NB * NB;
  float* npos = sq + NB;

  void* args[] = {(void*)&V, (void*)&labels, (void*)&Gp, (void*)&sq, (void*)&npos, (void*)&outp};
  hipLaunchCooperativeKernel((const void*)fused_kernel, dim3(256), dim3(256), args, 0, stream);
}

// Round 7
// 69.021 us; speedup vs baseline: 1.6423x; 1.6423x over previous
//
#include <hip/hip_runtime.h>

#define NB 384          // batch
#define ND 512          // dim
#define KS 8            // k-slices
#define FLT_BIG 3.0e38f

// ws layout (floats): Gp[8][384][384] @ 0 ; sq[384] ; npos[1]   (< 5 MB)
// Cost model (R2-R6 evidence): ~41us ws-poison fill + ~20us graph/restore
// residual are fixed harness costs; our controllable slice is ~8.5us.
// grid.sync() measured at ~40+us on MI355X (R6) -- never fuse via coop here.

// ---------- kernel A: split-K gram partials (no atomics) + sq + npos + out=0 ----------
// grid 175: blocks 0..167 = 8 k-slices x 21 upper tiles (mirror-stored);
//           blocks 168..173 = sq (64 rows each); block 174 = npos + zero out.
__global__ __launch_bounds__(256) void gram_prep_kernel(const float* __restrict__ V,
                                                        const int* __restrict__ labels,
                                                        float* __restrict__ Gp,
                                                        float* __restrict__ sq,
                                                        float* __restrict__ npos,
                                                        float* __restrict__ out0) {
  const int bx = blockIdx.x;
  const int tid = threadIdx.x;
  if (bx < 168) {
    __shared__ float As[64][68];
    __shared__ float Bs[64][68];
    const int ks = bx / 21;
    int rem = bx % 21;
    int ti = 0, cnt = 6;
    while (rem >= cnt) { rem -= cnt; --cnt; ++ti; }   // triangular tile pair
    const int tj = ti + rem;
    const int a0 = ti * 64, b0 = tj * 64, k0 = ks * 64;

#pragma unroll
    for (int it = 0; it < 4; ++it) {
      int f = tid + it * 256;            // float4 id 0..1023
      int row = f >> 4, c4 = (f & 15) << 2;
      *(float4*)&As[row][c4] = *(const float4*)&V[(size_t)(a0 + row) * ND + k0 + c4];
      *(float4*)&Bs[row][c4] = *(const float4*)&V[(size_t)(b0 + row) * ND + k0 + c4];
    }
    __syncthreads();

    const int tx = tid & 15, ty = tid >> 4;
    float acc[4][4] = {};
#pragma unroll
    for (int kk = 0; kk < 64; kk += 4) {
      float4 av[4], bv[4];
#pragma unroll
      for (int i = 0; i < 4; ++i) {
        av[i] = *(const float4*)&As[ty + 16 * i][kk];
        bv[i] = *(const float4*)&Bs[tx + 16 * i][kk];
      }
#pragma unroll
      for (int i = 0; i < 4; ++i)
#pragma unroll
        for (int j = 0; j < 4; ++j) {
          acc[i][j] = fmaf(av[i].x, bv[j].x, acc[i][j]);
          acc[i][j] = fmaf(av[i].y, bv[j].y, acc[i][j]);
          acc[i][j] = fmaf(av[i].z, bv[j].z, acc[i][j]);
          acc[i][j] = fmaf(av[i].w, bv[j].w, acc[i][j]);
        }
    }
    float* Gk = Gp + (size_t)ks * NB * NB;
#pragma unroll
    for (int i = 0; i < 4; ++i)
#pragma unroll
      for (int j = 0; j < 4; ++j) {
        const int ar = a0 + ty + 16 * i, bc = b0 + tx + 16 * j;
        Gk[(size_t)ar * NB + bc] = acc[i][j];
        Gk[(size_t)bc * NB + ar] = acc[i][j];   // symmetric mirror (identical value)
      }
  } else if (bx < 174) {
    // sq for 64 rows: 4 lanes per row
    const int r = (bx - 168) * 64 + (tid >> 2);
    const int q = tid & 3;
    const float4* p = (const float4*)(V + (size_t)r * ND + q * 128);
    float s = 0.f;
#pragma unroll 8
    for (int i = 0; i < 32; ++i) {
      float4 v = p[i];
      s += v.x * v.x + v.y * v.y + v.z * v.z + v.w * v.w;
    }
    s += __shfl_xor(s, 1);
    s += __shfl_xor(s, 2);
    if (q == 0) sq[r] = s;
  } else {
    // num_pos = sum_c count[c]^2 - NB ; zero the output slot
    __shared__ int cnt[64];
    if (tid < 64) cnt[tid] = 0;
    __syncthreads();
    for (int i = tid; i < NB; i += 256) atomicAdd(&cnt[labels[i]], 1);
    __syncthreads();
    if (tid < 64) {
      int c = cnt[tid];
      int s = c * c;
#pragma unroll
      for (int off = 32; off; off >>= 1) s += __shfl_xor(s, off);
      if (tid == 0) {
        npos[0] = (float)(s - NB);
        out0[0] = 0.0f;
      }
    }
  }
}

// ---------- kernel B: one wave per row a, no barriers ----------
__global__ __launch_bounds__(64) void loss_kernel(const float* __restrict__ Gp,
                                                  const float* __restrict__ sq,
                                                  const int* __restrict__ labels,
                                                  const float* __restrict__ npos,
                                                  float* __restrict__ out) {
  const int a = blockIdx.x;
  const int lane = threadIdx.x;
  const float sqa = sq[a];
  const int la = labels[a];

  float dk[6];
  int same[6];
  float neg_in = 0.0f;
#pragma unroll
  for (int i = 0; i < 6; ++i) {
    const int k = lane + (i << 6);
    // two independent partial-sum chains (shorter dependent-add latency)
    float g0 = 0.f, g1 = 0.f;
#pragma unroll
    for (int p = 0; p < KS; p += 2) {
      g0 += Gp[(size_t)p * NB * NB + (size_t)a * NB + k];
      g1 += Gp[(size_t)(p + 1) * NB * NB + (size_t)a * NB + k];
    }
    const float g = g0 + g1;
    float d2 = sqa + sq[k] - 2.0f * g;
    d2 = fmaxf(d2, 0.0f);
    float d = (d2 <= 0.0f) ? 0.0f : sqrtf(d2);
    if (k == a) d = 0.0f;               // zero diagonal (matches reference)
    dk[i] = d;
    same[i] = (labels[k] == la);
    if (!same[i]) neg_in = fmaxf(neg_in, d);   // row_min == 0 exactly
  }
#pragma unroll
  for (int off = 32; off; off >>= 1) neg_in = fmaxf(neg_in, __shfl_xor(neg_in, off));

  float rsum = 0.0f;
#pragma unroll 1
  for (int i = 0; i < 6; ++i) {
    const int k = lane + (i << 6);
    unsigned long long pm = __ballot(same[i] && (k != a));   // positives in this slice
    while (pm) {
      const int src = __builtin_ctzll(pm);
      pm &= pm - 1;
      const float db = __shfl(dk[i], src);   // d[a,b] broadcast
      float m = FLT_BIG;                     // min over negs with d[a,k] > db
#pragma unroll
      for (int t = 0; t < 6; ++t) {
        const float c = (!same[t] && dk[t] > db) ? dk[t] : FLT_BIG;
        m = fminf(m, c);
      }
#pragma unroll
      for (int off = 32; off; off >>= 1) m = fminf(m, __shfl_xor(m, off));
      const float semi = (m < 1.0e38f) ? m : neg_in;  // exists -> neg_out else neg_in
      rsum += fmaxf(db - semi + 1.0f, 0.0f);          // MARGIN = 1
    }
  }
  if (lane == 0) atomicAdd(out, rsum / npos[0]);
}

extern "C" void kernel_launch(void* const* d_in, const int* in_sizes, int n_in,
                              void* d_out, int out_size, void* d_ws, size_t ws_size,
                              hipStream_t stream) {
  const float* V = (const float*)d_in[0];
  const int* labels = (const int*)d_in[1];
  float* outp = (float*)d_out;
  float* Gp = (float*)d_ws;                         // 8*384*384 floats
  float* sq = Gp + (size_t)KS * NB * NB;
  float* npos = sq + NB;
  gram_prep_kernel<<<dim3(175), 256, 0, stream>>>(V, labels, Gp, sq, npos, outp);
  loss_kernel<<<dim3(NB), 64, 0, stream>>>(Gp, sq, labels, npos, outp);
}